// Round 1
// 257.914 us; speedup vs baseline: 1.0068x; 1.0068x over previous
//
#include <hip/hip_runtime.h>
#include <math.h>

#define B_ 2
#define T_ 2048
#define D_ 1024
#define H_ 16
#define HD_ 64
#define MAXLEN_ 2048
#define N3D_ 3072
#define M_ (B_ * T_)   // 4096
#define KA 1024        // GEMM K (plain bf16)

#define SCALE_L2E 0.18033688011116215f   // 0.125 * log2(e)
#define L2E 1.4426950408889634f

typedef unsigned short ushort_t;
typedef __attribute__((ext_vector_type(8))) short short8;
typedef __attribute__((ext_vector_type(4))) float floatx4;
#define MFMA16(a, b, c) __builtin_amdgcn_mfma_f32_16x16x32_bf16(a, b, c, 0, 0, 0)

static __device__ __forceinline__ ushort_t f2bf(float f) {
    unsigned u = __float_as_uint(f);
    unsigned r = (u + 0x7FFFu + ((u >> 16) & 1u)) >> 16;
    return (ushort_t)r;
}
// round-half-up bf16 pair pack: add 0x8000 then take hi16 of each via v_perm.
static __device__ __forceinline__ unsigned packrnu(float a, float b) {
    unsigned ua = __float_as_uint(a) + 0x8000u;
    unsigned ub = __float_as_uint(b) + 0x8000u;
    return __builtin_amdgcn_perm(ub, ua, 0x07060302u);
}

// async global->LDS, 16B per lane; lds dst = wave-uniform base + lane*16
static __device__ __forceinline__ void gld16(const ushort_t* g, ushort_t* l) {
    __builtin_amdgcn_global_load_lds(
        (const __attribute__((address_space(1))) void*)g,
        (__attribute__((address_space(3))) void*)l, 16, 0, 0);
}

// ---------------------------------------------------------------------------
// Fused precompute: rows [0, 8192) convert x|qkv_w|out_w fp32->bf16;
// rows [8192, 9216) project rel_pos @ rpe_w (4 rows/block, 1 per wave).
// ---------------------------------------------------------------------------
__global__ __launch_bounds__(256) void cvt_all(
    const float* __restrict__ x, const float* __restrict__ qw,
    const float* __restrict__ ow, const float* __restrict__ rel_pos,
    const float* __restrict__ rpe_w,
    ushort_t* __restrict__ Xc, ushort_t* __restrict__ QWc,
    ushort_t* __restrict__ OWc, float* __restrict__ biasp)
{
    const int row = blockIdx.x;
    if (row < M_ + N3D_ + D_) {
        const float* src; ushort_t* dst; int r;
        if (row < M_)            { src = x;  dst = Xc;  r = row; }
        else if (row < M_ + N3D_){ src = qw; dst = QWc; r = row - M_; }
        else                     { src = ow; dst = OWc; r = row - M_ - N3D_; }
        const int c = threadIdx.x * 4;
        float4 v = *(const float4*)(src + (size_t)r * 1024 + c);
        ushort4 hv;
        hv.x = f2bf(v.x); hv.y = f2bf(v.y); hv.z = f2bf(v.z); hv.w = f2bf(v.w);
        *(ushort4*)(dst + (size_t)r * KA + c) = hv;
    } else {
        const int wv = threadIdx.x >> 6, lane = threadIdx.x & 63;
        const int r = (row - (M_ + N3D_ + D_)) * 4 + wv;
        if (r < 2 * MAXLEN_ - 1) {
            float v = rel_pos[(size_t)r * HD_ + lane] * rpe_w[lane];
#pragma unroll
            for (int off = 32; off; off >>= 1) v += __shfl_down(v, off);
            if (lane == 0) biasp[r] = v * L2E;
        }
    }
}

// ---------------------------------------------------------------------------
// qkv MFMA GEMM. M=4096, N=3072, K=1024 bf16. 128x128 tile, 4 waves.
// v6: 2-phase double-buffered pipeline (T3 minimum recipe) + T1 XCD swizzle.
// Prefetch of K-step t+1 is issued BEFORE the ds_read+MFMA of step t; one
// vmcnt(0)+barrier per step placed after compute, so HBM/L2 latency drains
// under the 32-MFMA phase instead of serializing in front of it.
// Epilogue: Q -> Qs (pre-scaled by 0.125*log2e), K -> Khi, V -> Vt [B,H,HD,T].
// ---------------------------------------------------------------------------
__global__ __launch_bounds__(256) void qkv_mfma(
    const ushort_t* __restrict__ Ac, const ushort_t* __restrict__ Bc,
    const float* __restrict__ bias,
    ushort_t* __restrict__ Qs, ushort_t* __restrict__ Khi,
    ushort_t* __restrict__ Vt)
{
    __shared__ __align__(16) ushort_t As[2][16 * 512];   // 32 KB
    __shared__ __align__(16) ushort_t Bs[2][16 * 512];   // 32 KB
    const int tid = threadIdx.x;
    const int wv = tid >> 6, lane = tid & 63;
    const int l16 = lane & 15, quad = lane >> 4;
    const int wm = wv & 1, wn = wv >> 1;

    // T1: bijective XCD chunking. 768 blocks, 8 XCDs -> 96 consecutive
    // row-major tiles (4 full M-rows x 24 N-cols) per XCD => A-panels stay
    // L2-resident within one XCD.
    const int orig = blockIdx.y * 24 + blockIdx.x;
    const int swz = (orig & 7) * 96 + (orig >> 3);
    const int m0 = (swz / 24) * 128, n0 = (swz % 24) * 128;

    floatx4 acc[4][4];
#pragma unroll
    for (int i = 0; i < 4; ++i)
#pragma unroll
        for (int j = 0; j < 4; ++j) acc[i][j] = (floatx4){0.f, 0.f, 0.f, 0.f};

    auto stage = [&](int bufi, int kk) {
#pragma unroll
        for (int c = 0; c < 4; ++c) {
            const int b = wv * 4 + c;
            const int i = b >> 1, ks = b & 1;
            const int k = kk + ks * 32 + quad * 8;
            gld16(Ac + (size_t)(m0 + i * 16 + l16) * KA + k, As[bufi] + b * 512);
            gld16(Bc + (size_t)(n0 + i * 16 + l16) * KA + k, Bs[bufi] + b * 512);
        }
    };

    stage(0, 0);
    __syncthreads();

#pragma unroll 1
    for (int t = 0; t < 16; ++t) {
        const int cur = t & 1;
        if (t < 15) stage(cur ^ 1, (t + 1) * 64);   // prefetch next K-step
#pragma unroll
        for (int ks = 0; ks < 2; ++ks) {
            short8 af[4], bf[4];
#pragma unroll
            for (int ii = 0; ii < 4; ++ii)
                af[ii] = *(const short8*)(As[cur] + ((wm * 4 + ii) * 2 + ks) * 512 + lane * 8);
#pragma unroll
            for (int jj = 0; jj < 4; ++jj)
                bf[jj] = *(const short8*)(Bs[cur] + ((wn * 4 + jj) * 2 + ks) * 512 + lane * 8);
#pragma unroll
            for (int ii = 0; ii < 4; ++ii)
#pragma unroll
                for (int jj = 0; jj < 4; ++jj)
                    acc[ii][jj] = MFMA16(af[ii], bf[jj], acc[ii][jj]);
        }
        if (t < 15) __syncthreads();   // drains prefetch AFTER compute covered it
    }

#pragma unroll
    for (int ii = 0; ii < 4; ++ii) {
#pragma unroll
        for (int r = 0; r < 4; ++r) {
            const int m = m0 + wm * 64 + ii * 16 + quad * 4 + r;
            const int bb = m >> 11, t = m & 2047;
#pragma unroll
            for (int jj = 0; jj < 4; ++jj) {
                const int n = n0 + wn * 64 + jj * 16 + l16;
                const int c = n >> 10, h = (n >> 6) & 15, hd = n & 63;
                const float v = acc[ii][jj][r] + bias[n];
                const size_t idx = (((size_t)bb * H_ + h) * T_ + t) * HD_ + hd;
                if (c == 0) { Qs[idx] = f2bf(v * SCALE_L2E); }
                else if (c == 1) { Khi[idx] = f2bf(v); }
                else { Vt[(((size_t)bb * H_ + h) * HD_ + hd) * T_ + t] = f2bf(v); }
            }
        }
    }
}

// ---------------------------------------------------------------------------
// out MFMA GEMM. M=4096, N=1024, K=1024. 128x64 tile.
// v6: same 2-phase dbuf pipeline + T1 XCD swizzle (48 KB LDS, 3 blocks/CU).
// ---------------------------------------------------------------------------
__global__ __launch_bounds__(256) void out_mfma(
    const ushort_t* __restrict__ Ac, const ushort_t* __restrict__ Bc,
    const float* __restrict__ bias, float* __restrict__ Out)
{
    __shared__ __align__(16) ushort_t As[2][16 * 512];   // 32 KB
    __shared__ __align__(16) ushort_t Bs[2][8 * 512];    // 16 KB
    const int tid = threadIdx.x;
    const int wv = tid >> 6, lane = tid & 63;
    const int l16 = lane & 15, quad = lane >> 4;
    const int wm = wv & 1, wn = wv >> 1;

    // T1: 512 blocks -> 64 consecutive tiles (4 M-rows x 16 N-cols) per XCD.
    const int orig = blockIdx.y * 16 + blockIdx.x;
    const int swz = (orig & 7) * 64 + (orig >> 3);
    const int m0 = (swz >> 4) * 128, n0 = (swz & 15) * 64;

    floatx4 acc[4][2];
#pragma unroll
    for (int i = 0; i < 4; ++i)
#pragma unroll
        for (int j = 0; j < 2; ++j) acc[i][j] = (floatx4){0.f, 0.f, 0.f, 0.f};

    auto stage = [&](int bufi, int kk) {
#pragma unroll
        for (int c = 0; c < 4; ++c) {
            const int b = wv * 4 + c;
            const int i = b >> 1, ks = b & 1;
            const int k = kk + ks * 32 + quad * 8;
            gld16(Ac + (size_t)(m0 + i * 16 + l16) * KA + k, As[bufi] + b * 512);
        }
#pragma unroll
        for (int c = 0; c < 2; ++c) {
            const int b = wv * 2 + c;
            const int j = b >> 1, ks = b & 1;
            const int k = kk + ks * 32 + quad * 8;
            gld16(Bc + (size_t)(n0 + j * 16 + l16) * KA + k, Bs[bufi] + b * 512);
        }
    };

    stage(0, 0);
    __syncthreads();

#pragma unroll 1
    for (int t = 0; t < 16; ++t) {
        const int cur = t & 1;
        if (t < 15) stage(cur ^ 1, (t + 1) * 64);
#pragma unroll
        for (int ks = 0; ks < 2; ++ks) {
            short8 af[4], bf[2];
#pragma unroll
            for (int ii = 0; ii < 4; ++ii)
                af[ii] = *(const short8*)(As[cur] + ((wm * 4 + ii) * 2 + ks) * 512 + lane * 8);
#pragma unroll
            for (int jj = 0; jj < 2; ++jj)
                bf[jj] = *(const short8*)(Bs[cur] + ((wn * 2 + jj) * 2 + ks) * 512 + lane * 8);
#pragma unroll
            for (int ii = 0; ii < 4; ++ii)
#pragma unroll
                for (int jj = 0; jj < 2; ++jj)
                    acc[ii][jj] = MFMA16(af[ii], bf[jj], acc[ii][jj]);
        }
        if (t < 15) __syncthreads();
    }

#pragma unroll
    for (int ii = 0; ii < 4; ++ii) {
#pragma unroll
        for (int r = 0; r < 4; ++r) {
            const int m = m0 + wm * 64 + ii * 16 + quad * 4 + r;
#pragma unroll
            for (int jj = 0; jj < 2; ++jj) {
                const int n = n0 + wn * 32 + jj * 16 + l16;
                Out[(size_t)m * D_ + n] = acc[ii][jj][r] + bias[n];
            }
        }
    }
}

// ---------------------------------------------------------------------------
// Flash attention v5: v4 core + vmcnt-ordering fix.
// Bias float4s for tile t are loaded BEFORE the tile t+1 prefetch is issued,
// so consuming them waits only vmcnt(8) (prefetch may remain outstanding) --
// previously bias loads sat behind the prefetch in the in-order vmcnt queue,
// forcing a full prefetch drain every tile. Bias enters via MFMA C-operand.
// ---------------------------------------------------------------------------
__global__ __launch_bounds__(256) void attn_mfma(
    const ushort_t* __restrict__ Qs, const ushort_t* __restrict__ Khi,
    const ushort_t* __restrict__ Vt, const float* __restrict__ biasp,
    ushort_t* __restrict__ AOc)
{
    __shared__ __align__(16) ushort_t KS[2][8 * 512];   // 16 KB
    __shared__ __align__(16) ushort_t VS[2][8 * 512];   // 16 KB
    __shared__ __align__(16) ushort_t PS[4][2][1024];   // 16 KB: wave, qgroup

    // XCD swizzle: 16 q-tiles of one bh stay on one XCD slot
    const int i = blockIdx.x;
    const int j = i >> 3;
    const int bh = (i & 7) + 8 * (j >> 4);
    const int q0 = (j & 15) * 128;
    const int tid = threadIdx.x;
    const int wv = tid >> 6, lane = tid & 63;
    const int l16 = lane & 15, quad = lane >> 4;

    const int qw = q0 + wv * 32;

    // Q B-fragments for the wave's two 16-col groups (persistent)
    short8 qh[2][2];
#pragma unroll
    for (int u = 0; u < 2; ++u) {
        const size_t qoff = ((size_t)bh * T_ + qw + u * 16 + l16) * HD_ + quad * 8;
        qh[u][0] = *(const short8*)(Qs + qoff);
        qh[u][1] = *(const short8*)(Qs + qoff + 32);
    }

    float l_r[2] = {0.f, 0.f};
    floatx4 o_acc[4][2];
#pragma unroll
    for (int g2 = 0; g2 < 4; ++g2)
#pragma unroll
        for (int u = 0; u < 2; ++u) o_acc[g2][u] = (floatx4){0.f, 0.f, 0.f, 0.f};

    const ushort_t* gK = Khi + (size_t)bh * T_ * HD_;
    const ushort_t* gV = Vt + (size_t)bh * HD_ * T_;
    // bias window base for u=1 (u=0 base = this + 16); >= 0 for all lanes
    const int c0base = 2047 + quad * 4 - (qw + 16 + l16);
    const int qdbase = quad >> 1;

    const size_t kstage = (size_t)(wv * 16 + l16) * HD_ + quad * 8;
    const size_t vstage = (size_t)(wv * 16 + l16) * T_ + quad * 8;

    // prologue: stage tile 0 into buffer 0
    gld16(gK + kstage,      KS[0] + (wv * 2 + 0) * 512);
    gld16(gK + kstage + 32, KS[0] + (wv * 2 + 1) * 512);
    gld16(gV + vstage,      VS[0] + (wv * 2 + 0) * 512);
    gld16(gV + vstage + 32, VS[0] + (wv * 2 + 1) * 512);
    __syncthreads();

    for (int t = 0; t < 32; ++t) {
        const int k0 = t * 64;
        const int buf = t & 1, nbuf = buf ^ 1;

        // ---- bias loads FIRST (before prefetch -> clean vmcnt ordering) ----
        // f4[z] = biasp[c0base + k0 + z*16 .. +3]; u=0,g uses f4[g+1]; u=1,g uses f4[g]
        float4 f4[5];
        {
            const float* bp = biasp + (c0base + k0);
#pragma unroll
            for (int z = 0; z < 5; ++z)
                __builtin_memcpy(&f4[z], bp + z * 16, 16);
        }

        // ---- prefetch tile t+1 into the other buffer ----
        if (t < 31) {
            const size_t koff = kstage + (size_t)(k0 + 64) * HD_;
            gld16(gK + koff,      KS[nbuf] + (wv * 2 + 0) * 512);
            gld16(gK + koff + 32, KS[nbuf] + (wv * 2 + 1) * 512);
            const size_t voff = vstage + (size_t)(k0 + 64);
            gld16(gV + voff,      VS[nbuf] + (wv * 2 + 0) * 512);
            gld16(gV + voff + 32, VS[nbuf] + (wv * 2 + 1) * 512);
        }

        // ---- S^T = K x Q + bias (via C-operand); p = exp2(s) ----
#pragma unroll
        for (int g = 0; g < 4; ++g) {
            const short8 kh0 = *(const short8*)(KS[buf] + (g * 2 + 0) * 512 + lane * 8);
            const short8 kh1 = *(const short8*)(KS[buf] + (g * 2 + 1) * 512 + lane * 8);
            const int qd = 2 * (g & 1) + qdbase;
#pragma unroll
            for (int u = 0; u < 2; ++u) {
                const float4 bbv = f4[g + 1 - u];
                floatx4 a = (floatx4){bbv.x, bbv.y, bbv.z, bbv.w};
                a = MFMA16(kh0, qh[u][0], a);
                a = MFMA16(kh1, qh[u][1], a);
                const float p0 = __builtin_amdgcn_exp2f(a[0]);
                const float p1 = __builtin_amdgcn_exp2f(a[1]);
                const float p2 = __builtin_amdgcn_exp2f(a[2]);
                const float p3 = __builtin_amdgcn_exp2f(a[3]);
                l_r[u] += (p0 + p1) + (p2 + p3);
                uint2 pkd;
                pkd.x = packrnu(p0, p1);
                pkd.y = packrnu(p2, p3);
                *(uint2*)(PS[wv][u] + (g >> 1) * 512 + (qd * 16 + l16) * 8 + (quad & 1) * 4) = pkd;
            }
        }

        // ---- P frag reads (wave-internal dependency) ----
        short8 pf[2][2];
#pragma unroll
        for (int u = 0; u < 2; ++u) {
            pf[u][0] = *(const short8*)(PS[wv][u] + lane * 8);
            pf[u][1] = *(const short8*)(PS[wv][u] + 512 + lane * 8);
        }

        // ---- O^T += V^T P^T (V frags shared across q-groups) ----
#pragma unroll
        for (int g2 = 0; g2 < 4; ++g2) {
            const short8 v0 = *(const short8*)(VS[buf] + (g2 * 2 + 0) * 512 + lane * 8);
            const short8 v1 = *(const short8*)(VS[buf] + (g2 * 2 + 1) * 512 + lane * 8);
#pragma unroll
            for (int u = 0; u < 2; ++u) {
                o_acc[g2][u] = MFMA16(v0, pf[u][0], o_acc[g2][u]);
                o_acc[g2][u] = MFMA16(v1, pf[u][1], o_acc[g2][u]);
            }
        }
        __syncthreads();
    }

    // ---- deferred l reduction + epilogue ----
    const int bb2 = bh >> 4, h2 = bh & 15;
#pragma unroll
    for (int u = 0; u < 2; ++u) {
        l_r[u] += __shfl_xor(l_r[u], 16);
        l_r[u] += __shfl_xor(l_r[u], 32);
        const float inv = 1.0f / l_r[u];
        const size_t m = (size_t)bb2 * T_ + qw + u * 16 + l16;
#pragma unroll
        for (int g2 = 0; g2 < 4; ++g2) {
            uint2 pk;
            pk.x = packrnu(o_acc[g2][u][0] * inv, o_acc[g2][u][1] * inv);
            pk.y = packrnu(o_acc[g2][u][2] * inv, o_acc[g2][u][3] * inv);
            *(uint2*)(AOc + m * KA + h2 * 64 + g2 * 16 + quad * 4) = pk;
        }
    }
}

// ---------------------------------------------------------------------------
extern "C" void kernel_launch(void* const* d_in, const int* in_sizes, int n_in,
                              void* d_out, int out_size, void* d_ws, size_t ws_size,
                              hipStream_t stream)
{
    const float* x       = (const float*)d_in[0];
    const float* qkv_w   = (const float*)d_in[1];
    const float* qkv_b   = (const float*)d_in[2];
    const float* out_w   = (const float*)d_in[3];
    const float* out_b   = (const float*)d_in[4];
    const float* rel_pos = (const float*)d_in[5];
    const float* rpe_w   = (const float*)d_in[6];
    float* out = (float*)d_out;

    const size_t QE = (size_t)B_ * H_ * T_ * HD_;  // 4,194,304
    ushort_t* Qs  = (ushort_t*)d_ws;
    ushort_t* Khi = Qs  + QE;
    ushort_t* Vt  = Khi + QE;
    ushort_t* Xc  = Vt  + QE;                  // [4096][1024]
    ushort_t* QWc = Xc  + (size_t)M_ * KA;     // [3072][1024]
    ushort_t* OWc = QWc + (size_t)N3D_ * KA;   // [1024][1024]
    ushort_t* AOc = OWc + (size_t)D_ * KA;     // [4096][1024]
    float* biasp  = (float*)(AOc + (size_t)M_ * KA);

    cvt_all<<<M_ + N3D_ + D_ + 1024, 256, 0, stream>>>(
        x, qkv_w, out_w, rel_pos, rpe_w, Xc, QWc, OWc, biasp);

    qkv_mfma<<<dim3(N3D_ / 128, M_ / 128), 256, 0, stream>>>(
        Xc, QWc, qkv_b, Qs, Khi, Vt);
    attn_mfma<<<512, 256, 0, stream>>>(Qs, Khi, Vt, biasp, AOc);
    out_mfma<<<dim3(D_ / 64, M_ / 128), 256, 0, stream>>>(
        AOc, OWc, out_b, out);
}

// Round 2
// 241.885 us; speedup vs baseline: 1.0735x; 1.0663x over previous
//
#include <hip/hip_runtime.h>
#include <math.h>

#define B_ 2
#define T_ 2048
#define D_ 1024
#define H_ 16
#define HD_ 64
#define MAXLEN_ 2048
#define N3D_ 3072
#define M_ (B_ * T_)   // 4096
#define KA 1024        // GEMM K (plain bf16)

#define SCALE_L2E 0.18033688011116215f   // 0.125 * log2(e)
#define L2E 1.4426950408889634f

typedef unsigned short ushort_t;
typedef __attribute__((ext_vector_type(8))) short short8;
typedef __attribute__((ext_vector_type(4))) float floatx4;
#define MFMA16(a, b, c) __builtin_amdgcn_mfma_f32_16x16x32_bf16(a, b, c, 0, 0, 0)

static __device__ __forceinline__ ushort_t f2bf(float f) {
    unsigned u = __float_as_uint(f);
    unsigned r = (u + 0x7FFFu + ((u >> 16) & 1u)) >> 16;
    return (ushort_t)r;
}
// round-half-up bf16 pair pack: add 0x8000 then take hi16 of each via v_perm.
static __device__ __forceinline__ unsigned packrnu(float a, float b) {
    unsigned ua = __float_as_uint(a) + 0x8000u;
    unsigned ub = __float_as_uint(b) + 0x8000u;
    return __builtin_amdgcn_perm(ub, ua, 0x07060302u);
}

// async global->LDS, 16B per lane; lds dst = wave-uniform base + lane*16
static __device__ __forceinline__ void gld16(const ushort_t* g, ushort_t* l) {
    __builtin_amdgcn_global_load_lds(
        (const __attribute__((address_space(1))) void*)g,
        (__attribute__((address_space(3))) void*)l, 16, 0, 0);
}

// ---------------------------------------------------------------------------
// Fused precompute: rows [0, 8192) convert x|qkv_w|out_w fp32->bf16;
// rows [8192, 9216) project rel_pos @ rpe_w (4 rows/block, 1 per wave).
// ---------------------------------------------------------------------------
__global__ __launch_bounds__(256) void cvt_all(
    const float* __restrict__ x, const float* __restrict__ qw,
    const float* __restrict__ ow, const float* __restrict__ rel_pos,
    const float* __restrict__ rpe_w,
    ushort_t* __restrict__ Xc, ushort_t* __restrict__ QWc,
    ushort_t* __restrict__ OWc, float* __restrict__ biasp)
{
    const int row = blockIdx.x;
    if (row < M_ + N3D_ + D_) {
        const float* src; ushort_t* dst; int r;
        if (row < M_)            { src = x;  dst = Xc;  r = row; }
        else if (row < M_ + N3D_){ src = qw; dst = QWc; r = row - M_; }
        else                     { src = ow; dst = OWc; r = row - M_ - N3D_; }
        const int c = threadIdx.x * 4;
        float4 v = *(const float4*)(src + (size_t)r * 1024 + c);
        ushort4 hv;
        hv.x = f2bf(v.x); hv.y = f2bf(v.y); hv.z = f2bf(v.z); hv.w = f2bf(v.w);
        *(ushort4*)(dst + (size_t)r * KA + c) = hv;
    } else {
        const int wv = threadIdx.x >> 6, lane = threadIdx.x & 63;
        const int r = (row - (M_ + N3D_ + D_)) * 4 + wv;
        if (r < 2 * MAXLEN_ - 1) {
            float v = rel_pos[(size_t)r * HD_ + lane] * rpe_w[lane];
#pragma unroll
            for (int off = 32; off; off >>= 1) v += __shfl_down(v, off);
            if (lane == 0) biasp[r] = v * L2E;
        }
    }
}

// ---------------------------------------------------------------------------
// qkv MFMA GEMM v7: 256x256 tile, BK=64, 8 waves (512 thr), 8-phase schedule
// with counted vmcnt (T3+T4) + setprio (T5). Fragment-contiguous LDS (each
// 16x32 frag = 1 KB slot, lane*16B) => zero bank conflicts, no T2 needed.
// Per phase: {ds_read subtile | stage 1 unit (2 gld16/thread) | s_barrier |
// setprio(1) 16 MFMA setprio(0) | s_barrier}; vmcnt(4) only at phases 4, 8.
// Stage cadence (X=even tile buf0, Y=odd tile buf1, X'=next even, Y'=next odd):
//   ph1:Y.Alo ph2:Y.Ahi ph3:X'.Blo ph4:X'.Bhi [vm4]
//   ph5:X'.Alo ph6:X'.Ahi ph7:Y'.Blo ph8:Y'.Bhi [vm4]
// Hazards: B regions last read ph2/ph6, A regions ph3/ph7 -> every stage-issue
// is >=1 barrier after last reader; vmcnt(4) leaves exactly the 2 youngest
// units in flight so every consumed tile is fully landed at its boundary.
// ---------------------------------------------------------------------------
__global__ __launch_bounds__(512, 2) void qkv_mfma(
    const ushort_t* __restrict__ Ac, const ushort_t* __restrict__ Bc,
    const float* __restrict__ bias,
    ushort_t* __restrict__ Qs, ushort_t* __restrict__ Khi,
    ushort_t* __restrict__ Vt)
{
    // [buf][A=0/B=1][32 frag slots x 512 ushorts] = 128 KiB
    __shared__ __align__(16) ushort_t LDS[2][2][32 * 512];

    const int tid = threadIdx.x;
    const int wv = tid >> 6, lane = tid & 63;
    const int l16 = lane & 15, quad = lane >> 4;
    const int wr = wv >> 2, wc = wv & 3;   // wave grid 2M x 4N, per-wave 128x64

    // T1: bijective chunked swizzle; 192 blocks, 24/XCD contiguous.
    const int orig = blockIdx.y * 12 + blockIdx.x;
    const int swz = (orig & 7) * 24 + (orig >> 3);
    const int m0 = (swz / 12) * 256, n0 = (swz % 12) * 256;

    floatx4 acc[8][4];
#pragma unroll
    for (int i = 0; i < 8; ++i)
#pragma unroll
        for (int j = 0; j < 4; ++j) acc[i][j] = (floatx4){0.f, 0.f, 0.f, 0.f};

    short8 af[4][2];      // current m-subtile (4 m-frags x 2 ks)
    short8 bf[2][2][2];   // both n-subtiles (ni, jj, ks)

#define BARX() asm volatile("s_barrier" ::: "memory")
#define WAITVM(n) asm volatile("s_waitcnt vmcnt(" #n ")" ::: "memory")

// stage one unit: wave wv stages frag I = unit*8+wv, both ks (2 gld16/thread)
#define STAGE(bufi, ab, unit, tile) do {                                      \
    const ushort_t* _src = (ab) ? Bc : Ac;                                    \
    const int _rc = (ab) ? n0 : m0;                                           \
    const int _I = (unit) * 8 + wv;                                           \
    const ushort_t* _g = _src + (size_t)(_rc + _I * 16 + l16) * KA            \
                              + ((tile) * 64 + quad * 8);                     \
    ushort_t* _l = &LDS[bufi][ab][(_I * 2) * 512];                            \
    gld16(_g, _l);                                                            \
    gld16(_g + 32, _l + 512);                                                 \
} while (0)

#define RD_AF(bufi, mi) do {                                                  \
    _Pragma("unroll") for (int ii = 0; ii < 4; ++ii) {                        \
        const int _I = wr * 8 + (mi) * 4 + ii;                                \
        af[ii][0] = *(const short8*)(&LDS[bufi][0][(_I * 2 + 0) * 512] + lane * 8); \
        af[ii][1] = *(const short8*)(&LDS[bufi][0][(_I * 2 + 1) * 512] + lane * 8); \
    } } while (0)

#define RD_BF(bufi, ni) do {                                                  \
    _Pragma("unroll") for (int jj = 0; jj < 2; ++jj) {                        \
        const int _I = wc * 4 + (ni) * 2 + jj;                                \
        bf[ni][jj][0] = *(const short8*)(&LDS[bufi][1][(_I * 2 + 0) * 512] + lane * 8); \
        bf[ni][jj][1] = *(const short8*)(&LDS[bufi][1][(_I * 2 + 1) * 512] + lane * 8); \
    } } while (0)

#define MM(mi, ni) do {                                                       \
    __builtin_amdgcn_s_setprio(1);                                            \
    _Pragma("unroll") for (int ii = 0; ii < 4; ++ii)                          \
    _Pragma("unroll") for (int jj = 0; jj < 2; ++jj) {                        \
        acc[(mi)*4+ii][(ni)*2+jj] = MFMA16(af[ii][0], bf[ni][jj][0], acc[(mi)*4+ii][(ni)*2+jj]); \
        acc[(mi)*4+ii][(ni)*2+jj] = MFMA16(af[ii][1], bf[ni][jj][1], acc[(mi)*4+ii][(ni)*2+jj]); \
    }                                                                         \
    __builtin_amdgcn_s_setprio(0);                                            \
} while (0)

    // ---- prologue: tile0 (X=buf0) fully + tile1's B halves (steady cadence)
    STAGE(0, 1, 0, 0); STAGE(0, 1, 1, 0);
    STAGE(0, 0, 0, 0); STAGE(0, 0, 1, 0);
    STAGE(1, 1, 0, 1); STAGE(1, 1, 1, 1);
    WAITVM(4);          // tile0 landed; tile1.B (4 loads) still in flight
    BARX();

#pragma unroll 1
    for (int j = 0; j < 8; ++j) {
        const int tY  = 2 * j + 1;
        const int tX2 = (2 * j + 2) & 15;   // wrap: tail stages valid-but-dead
        const int tY2 = (2 * j + 3) & 15;
        // ---- tile 2j in buf0 ----
        RD_AF(0, 0); RD_BF(0, 0); STAGE(1, 0, 0, tY);  BARX(); MM(0, 0); BARX();
        RD_BF(0, 1);              STAGE(1, 0, 1, tY);  BARX(); MM(0, 1); BARX();
        RD_AF(0, 1);              STAGE(0, 1, 0, tX2); BARX(); MM(1, 0); BARX();
                                  STAGE(0, 1, 1, tX2); BARX(); MM(1, 1);
        WAITVM(4); BARX();
        // ---- tile 2j+1 in buf1 ----
        RD_AF(1, 0); RD_BF(1, 0); STAGE(0, 0, 0, tX2); BARX(); MM(0, 0); BARX();
        RD_BF(1, 1);              STAGE(0, 0, 1, tX2); BARX(); MM(0, 1); BARX();
        RD_AF(1, 1);              STAGE(1, 1, 0, tY2); BARX(); MM(1, 0); BARX();
                                  STAGE(1, 1, 1, tY2); BARX(); MM(1, 1);
        WAITVM(4); BARX();
    }

#undef BARX
#undef WAITVM
#undef STAGE
#undef RD_AF
#undef RD_BF
#undef MM

    // ---- epilogue: scatter to Qs (scaled), Khi, Vt ----
#pragma unroll
    for (int mi = 0; mi < 8; ++mi) {
#pragma unroll
        for (int r = 0; r < 4; ++r) {
            const int m = m0 + wr * 128 + mi * 16 + quad * 4 + r;
            const int bb = m >> 11, t = m & 2047;
#pragma unroll
            for (int jj = 0; jj < 4; ++jj) {
                const int n = n0 + wc * 64 + jj * 16 + l16;
                const int c = n >> 10, h = (n >> 6) & 15, hd = n & 63;
                const float v = acc[mi][jj][r] + bias[n];
                const size_t idx = (((size_t)bb * H_ + h) * T_ + t) * HD_ + hd;
                if (c == 0) { Qs[idx] = f2bf(v * SCALE_L2E); }
                else if (c == 1) { Khi[idx] = f2bf(v); }
                else { Vt[(((size_t)bb * H_ + h) * HD_ + hd) * T_ + t] = f2bf(v); }
            }
        }
    }
}

// ---------------------------------------------------------------------------
// out MFMA GEMM. M=4096, N=1024, K=1024. 128x64 tile.
// 2-phase dbuf pipeline + T1 XCD swizzle (48 KB LDS).
// ---------------------------------------------------------------------------
__global__ __launch_bounds__(256) void out_mfma(
    const ushort_t* __restrict__ Ac, const ushort_t* __restrict__ Bc,
    const float* __restrict__ bias, float* __restrict__ Out)
{
    __shared__ __align__(16) ushort_t As[2][16 * 512];   // 32 KB
    __shared__ __align__(16) ushort_t Bs[2][8 * 512];    // 16 KB
    const int tid = threadIdx.x;
    const int wv = tid >> 6, lane = tid & 63;
    const int l16 = lane & 15, quad = lane >> 4;
    const int wm = wv & 1, wn = wv >> 1;

    const int orig = blockIdx.y * 16 + blockIdx.x;
    const int swz = (orig & 7) * 64 + (orig >> 3);
    const int m0 = (swz >> 4) * 128, n0 = (swz & 15) * 64;

    floatx4 acc[4][2];
#pragma unroll
    for (int i = 0; i < 4; ++i)
#pragma unroll
        for (int j = 0; j < 2; ++j) acc[i][j] = (floatx4){0.f, 0.f, 0.f, 0.f};

    auto stage = [&](int bufi, int kk) {
#pragma unroll
        for (int c = 0; c < 4; ++c) {
            const int b = wv * 4 + c;
            const int i = b >> 1, ks = b & 1;
            const int k = kk + ks * 32 + quad * 8;
            gld16(Ac + (size_t)(m0 + i * 16 + l16) * KA + k, As[bufi] + b * 512);
        }
#pragma unroll
        for (int c = 0; c < 2; ++c) {
            const int b = wv * 2 + c;
            const int j = b >> 1, ks = b & 1;
            const int k = kk + ks * 32 + quad * 8;
            gld16(Bc + (size_t)(n0 + j * 16 + l16) * KA + k, Bs[bufi] + b * 512);
        }
    };

    stage(0, 0);
    __syncthreads();

#pragma unroll 1
    for (int t = 0; t < 16; ++t) {
        const int cur = t & 1;
        if (t < 15) stage(cur ^ 1, (t + 1) * 64);
#pragma unroll
        for (int ks = 0; ks < 2; ++ks) {
            short8 af[4], bf[2];
#pragma unroll
            for (int ii = 0; ii < 4; ++ii)
                af[ii] = *(const short8*)(As[cur] + ((wm * 4 + ii) * 2 + ks) * 512 + lane * 8);
#pragma unroll
            for (int jj = 0; jj < 2; ++jj)
                bf[jj] = *(const short8*)(Bs[cur] + ((wn * 2 + jj) * 2 + ks) * 512 + lane * 8);
#pragma unroll
            for (int ii = 0; ii < 4; ++ii)
#pragma unroll
                for (int jj = 0; jj < 2; ++jj)
                    acc[ii][jj] = MFMA16(af[ii], bf[jj], acc[ii][jj]);
        }
        if (t < 15) __syncthreads();
    }

#pragma unroll
    for (int ii = 0; ii < 4; ++ii) {
#pragma unroll
        for (int r = 0; r < 4; ++r) {
            const int m = m0 + wm * 64 + ii * 16 + quad * 4 + r;
#pragma unroll
            for (int jj = 0; jj < 2; ++jj) {
                const int n = n0 + wn * 32 + jj * 16 + l16;
                Out[(size_t)m * D_ + n] = acc[ii][jj][r] + bias[n];
            }
        }
    }
}

// ---------------------------------------------------------------------------
// Flash attention v5: v4 core + vmcnt-ordering fix.
// Bias float4s for tile t are loaded BEFORE the tile t+1 prefetch is issued,
// so consuming them waits only vmcnt(8) (prefetch may remain outstanding).
// Bias enters via MFMA C-operand.
// ---------------------------------------------------------------------------
__global__ __launch_bounds__(256) void attn_mfma(
    const ushort_t* __restrict__ Qs, const ushort_t* __restrict__ Khi,
    const ushort_t* __restrict__ Vt, const float* __restrict__ biasp,
    ushort_t* __restrict__ AOc)
{
    __shared__ __align__(16) ushort_t KS[2][8 * 512];   // 16 KB
    __shared__ __align__(16) ushort_t VS[2][8 * 512];   // 16 KB
    __shared__ __align__(16) ushort_t PS[4][2][1024];   // 16 KB: wave, qgroup

    // XCD swizzle: 16 q-tiles of one bh stay on one XCD slot
    const int i = blockIdx.x;
    const int j = i >> 3;
    const int bh = (i & 7) + 8 * (j >> 4);
    const int q0 = (j & 15) * 128;
    const int tid = threadIdx.x;
    const int wv = tid >> 6, lane = tid & 63;
    const int l16 = lane & 15, quad = lane >> 4;

    const int qw = q0 + wv * 32;

    // Q B-fragments for the wave's two 16-col groups (persistent)
    short8 qh[2][2];
#pragma unroll
    for (int u = 0; u < 2; ++u) {
        const size_t qoff = ((size_t)bh * T_ + qw + u * 16 + l16) * HD_ + quad * 8;
        qh[u][0] = *(const short8*)(Qs + qoff);
        qh[u][1] = *(const short8*)(Qs + qoff + 32);
    }

    float l_r[2] = {0.f, 0.f};
    floatx4 o_acc[4][2];
#pragma unroll
    for (int g2 = 0; g2 < 4; ++g2)
#pragma unroll
        for (int u = 0; u < 2; ++u) o_acc[g2][u] = (floatx4){0.f, 0.f, 0.f, 0.f};

    const ushort_t* gK = Khi + (size_t)bh * T_ * HD_;
    const ushort_t* gV = Vt + (size_t)bh * HD_ * T_;
    // bias window base for u=1 (u=0 base = this + 16); >= 0 for all lanes
    const int c0base = 2047 + quad * 4 - (qw + 16 + l16);
    const int qdbase = quad >> 1;

    const size_t kstage = (size_t)(wv * 16 + l16) * HD_ + quad * 8;
    const size_t vstage = (size_t)(wv * 16 + l16) * T_ + quad * 8;

    // prologue: stage tile 0 into buffer 0
    gld16(gK + kstage,      KS[0] + (wv * 2 + 0) * 512);
    gld16(gK + kstage + 32, KS[0] + (wv * 2 + 1) * 512);
    gld16(gV + vstage,      VS[0] + (wv * 2 + 0) * 512);
    gld16(gV + vstage + 32, VS[0] + (wv * 2 + 1) * 512);
    __syncthreads();

    for (int t = 0; t < 32; ++t) {
        const int k0 = t * 64;
        const int buf = t & 1, nbuf = buf ^ 1;

        // ---- bias loads FIRST (before prefetch -> clean vmcnt ordering) ----
        float4 f4[5];
        {
            const float* bp = biasp + (c0base + k0);
#pragma unroll
            for (int z = 0; z < 5; ++z)
                __builtin_memcpy(&f4[z], bp + z * 16, 16);
        }

        // ---- prefetch tile t+1 into the other buffer ----
        if (t < 31) {
            const size_t koff = kstage + (size_t)(k0 + 64) * HD_;
            gld16(gK + koff,      KS[nbuf] + (wv * 2 + 0) * 512);
            gld16(gK + koff + 32, KS[nbuf] + (wv * 2 + 1) * 512);
            const size_t voff = vstage + (size_t)(k0 + 64);
            gld16(gV + voff,      VS[nbuf] + (wv * 2 + 0) * 512);
            gld16(gV + voff + 32, VS[nbuf] + (wv * 2 + 1) * 512);
        }

        // ---- S^T = K x Q + bias (via C-operand); p = exp2(s) ----
#pragma unroll
        for (int g = 0; g < 4; ++g) {
            const short8 kh0 = *(const short8*)(KS[buf] + (g * 2 + 0) * 512 + lane * 8);
            const short8 kh1 = *(const short8*)(KS[buf] + (g * 2 + 1) * 512 + lane * 8);
            const int qd = 2 * (g & 1) + qdbase;
#pragma unroll
            for (int u = 0; u < 2; ++u) {
                const float4 bbv = f4[g + 1 - u];
                floatx4 a = (floatx4){bbv.x, bbv.y, bbv.z, bbv.w};
                a = MFMA16(kh0, qh[u][0], a);
                a = MFMA16(kh1, qh[u][1], a);
                const float p0 = __builtin_amdgcn_exp2f(a[0]);
                const float p1 = __builtin_amdgcn_exp2f(a[1]);
                const float p2 = __builtin_amdgcn_exp2f(a[2]);
                const float p3 = __builtin_amdgcn_exp2f(a[3]);
                l_r[u] += (p0 + p1) + (p2 + p3);
                uint2 pkd;
                pkd.x = packrnu(p0, p1);
                pkd.y = packrnu(p2, p3);
                *(uint2*)(PS[wv][u] + (g >> 1) * 512 + (qd * 16 + l16) * 8 + (quad & 1) * 4) = pkd;
            }
        }

        // ---- P frag reads (wave-internal dependency) ----
        short8 pf[2][2];
#pragma unroll
        for (int u = 0; u < 2; ++u) {
            pf[u][0] = *(const short8*)(PS[wv][u] + lane * 8);
            pf[u][1] = *(const short8*)(PS[wv][u] + 512 + lane * 8);
        }

        // ---- O^T += V^T P^T (V frags shared across q-groups) ----
#pragma unroll
        for (int g2 = 0; g2 < 4; ++g2) {
            const short8 v0 = *(const short8*)(VS[buf] + (g2 * 2 + 0) * 512 + lane * 8);
            const short8 v1 = *(const short8*)(VS[buf] + (g2 * 2 + 1) * 512 + lane * 8);
#pragma unroll
            for (int u = 0; u < 2; ++u) {
                o_acc[g2][u] = MFMA16(v0, pf[u][0], o_acc[g2][u]);
                o_acc[g2][u] = MFMA16(v1, pf[u][1], o_acc[g2][u]);
            }
        }
        __syncthreads();
    }

    // ---- deferred l reduction + epilogue ----
    const int bb2 = bh >> 4, h2 = bh & 15;
#pragma unroll
    for (int u = 0; u < 2; ++u) {
        l_r[u] += __shfl_xor(l_r[u], 16);
        l_r[u] += __shfl_xor(l_r[u], 32);
        const float inv = 1.0f / l_r[u];
        const size_t m = (size_t)bb2 * T_ + qw + u * 16 + l16;
#pragma unroll
        for (int g2 = 0; g2 < 4; ++g2) {
            uint2 pk;
            pk.x = packrnu(o_acc[g2][u][0] * inv, o_acc[g2][u][1] * inv);
            pk.y = packrnu(o_acc[g2][u][2] * inv, o_acc[g2][u][3] * inv);
            *(uint2*)(AOc + m * KA + h2 * 64 + g2 * 16 + quad * 4) = pk;
        }
    }
}

// ---------------------------------------------------------------------------
extern "C" void kernel_launch(void* const* d_in, const int* in_sizes, int n_in,
                              void* d_out, int out_size, void* d_ws, size_t ws_size,
                              hipStream_t stream)
{
    const float* x       = (const float*)d_in[0];
    const float* qkv_w   = (const float*)d_in[1];
    const float* qkv_b   = (const float*)d_in[2];
    const float* out_w   = (const float*)d_in[3];
    const float* out_b   = (const float*)d_in[4];
    const float* rel_pos = (const float*)d_in[5];
    const float* rpe_w   = (const float*)d_in[6];
    float* out = (float*)d_out;

    const size_t QE = (size_t)B_ * H_ * T_ * HD_;  // 4,194,304
    ushort_t* Qs  = (ushort_t*)d_ws;
    ushort_t* Khi = Qs  + QE;
    ushort_t* Vt  = Khi + QE;
    ushort_t* Xc  = Vt  + QE;                  // [4096][1024]
    ushort_t* QWc = Xc  + (size_t)M_ * KA;     // [3072][1024]
    ushort_t* OWc = QWc + (size_t)N3D_ * KA;   // [1024][1024]
    ushort_t* AOc = OWc + (size_t)D_ * KA;     // [4096][1024]
    float* biasp  = (float*)(AOc + (size_t)M_ * KA);

    cvt_all<<<M_ + N3D_ + D_ + 1024, 256, 0, stream>>>(
        x, qkv_w, out_w, rel_pos, rpe_w, Xc, QWc, OWc, biasp);

    qkv_mfma<<<dim3(12, 16), 512, 0, stream>>>(
        Xc, QWc, qkv_b, Qs, Khi, Vt);
    attn_mfma<<<512, 256, 0, stream>>>(Qs, Khi, Vt, biasp, AOc);
    out_mfma<<<dim3(D_ / 64, M_ / 128), 256, 0, stream>>>(
        AOc, OWc, out_b, out);
}